// Round 3
// baseline (283.723 us; speedup 1.0000x reference)
//
#include <hip/hip_runtime.h>
#include <math.h>

#define BATCH 32
#define T 1024
#define F 768

// Workspace layout (NO zero-init required anywhere; k1 zeroes the counters):
//   [0, 8192)        : u64  best[1024]     one packed (p,idx) candidate per K1 block
//   [8192, 40960)    : f32x4 part[2048]    (den, n0, n1, 0) per K3 block
//   [40960, 41088)   : u32  cnt[32]        per-batch completion counters (k1 zeroes)
//   [65536, 589824)  : f32x4 stats[32768]  (p, y0, y1, inv_norm) per token

__device__ __forceinline__ void load_row(const float* __restrict__ p, int lane, float4 v[3]) {
    #pragma unroll
    for (int j = 0; j < 3; ++j) v[j] = *(const float4*)(p + j * 256 + lane * 4);
}

// ---------------------------------------------------------------------------
// K1: per-token stats + per-block argmax candidate (no atomics).
// grid = 1024 blocks (32/batch), 4 waves, 32 tokens/block, 8 iters/wave.
// Also zeroes the 32 per-batch counters used by K3's fused finalize
// (kernel-boundary release/acquire makes them visible device-wide).
// ---------------------------------------------------------------------------
__global__ __launch_bounds__(256, 4) void k1_token_stats(
    const float* __restrict__ x, const float* __restrict__ fc_w,
    const float* __restrict__ fc_b, const float* __restrict__ fc_final_w,
    float4* __restrict__ stats, unsigned long long* __restrict__ best,
    unsigned int* __restrict__ cnt)
{
    const int wave = threadIdx.x >> 6;
    const int lane = threadIdx.x & 63;
    const int b     = blockIdx.x >> 5;          // 32 blocks per batch
    const int tbase = (blockIdx.x & 31) * 32;   // token base within batch

    if ((blockIdx.x & 31) == 0 && threadIdx.x == 0)
        cnt[b] = 0u;                             // re-zero every iteration

    // hoist weights to registers; fc_w rows collapse to their difference
    float4 wd[3], f0[3], f1[3];
    #pragma unroll
    for (int j = 0; j < 3; ++j) {
        const int off = j * 256 + lane * 4;
        float4 a = *(const float4*)(fc_w + off);
        float4 c = *(const float4*)(fc_w + F + off);
        wd[j] = make_float4(a.x - c.x, a.y - c.y, a.z - c.z, a.w - c.w);
        f0[j] = *(const float4*)(fc_final_w + off);
        f1[j] = *(const float4*)(fc_final_w + F + off);
    }
    const float bias01 = fc_b[0] - fc_b[1];

    const float* tok0 = x + ((size_t)b * T + tbase + wave) * F;

    float bp = -1.f; int bidx = 0;              // wave-local argmax (uniform)
    float4 buf[3][3];                           // 3-slot rotation, 2-deep prefetch
    load_row(tok0,           lane, buf[0]);
    load_row(tok0 + 4 * F,   lane, buf[1]);
    #pragma unroll
    for (int it = 0; it < 8; ++it) {
        const int t = tbase + it * 4 + wave;
        if (it < 6)                              // prefetch token it+2
            load_row(tok0 + (it + 2) * 4 * F, lane, buf[(it + 2) % 3]);
        const float4* v = buf[it % 3];
        float asq = 0.f, da = 0.f, a0 = 0.f, a1 = 0.f;
        #pragma unroll
        for (int j = 0; j < 3; ++j) {
            float4 w = v[j];
            asq += w.x*w.x     + w.y*w.y     + w.z*w.z     + w.w*w.w;
            da  += w.x*wd[j].x + w.y*wd[j].y + w.z*wd[j].z + w.w*wd[j].w;
            a0  += w.x*f0[j].x + w.y*f0[j].y + w.z*f0[j].z + w.w*f0[j].w;
            a1  += w.x*f1[j].x + w.y*f1[j].y + w.z*f1[j].z + w.w*f1[j].w;
        }
        // packed reduce-scatter over lane quadrants:
        //   q0 -> asq, q16 -> da, q32 -> a0, q48 -> a1
        const bool hi32 = (lane & 32) != 0;
        const bool hi16 = (lane & 16) != 0;
        float s1 = hi32 ? asq : a0;                 // give away
        float r1 = __shfl_xor(s1, 32);
        float u  = (hi32 ? a0 : asq) + r1;          // keep mine + partner's
        float s2 = hi32 ? da : a1;
        float r2 = __shfl_xor(s2, 32);
        float v2 = (hi32 ? a1 : da) + r2;
        float s3 = hi16 ? u : v2;
        float r3 = __shfl_xor(s3, 16);
        float w  = (hi16 ? v2 : u) + r3;
        #pragma unroll
        for (int d = 8; d > 0; d >>= 1) w += __shfl_xor(w, d);
        const float da_t = __shfl(w, 16);           // uniform broadcasts
        const float a0_t = __shfl(w, 32);
        const float a1_t = __shfl(w, 48);
        const float p = 1.f / (1.f + expf(da_t + bias01));  // softmax(logits)[1]
        if (lane == 0)                               // lane0's w == asq total
            stats[(size_t)b * T + t] = make_float4(p, a0_t, a1_t, 1.f / sqrtf(w));
        if (p > bp) { bp = p; bidx = t; }            // strict > keeps first max
    }

    // block candidate -> distinct slot; packed so plain u64 max == numpy argmax:
    // p > 0 => float bits order-preserving; low word 0xFFFFFFFF-idx => first-max ties
    __shared__ float sp[4]; __shared__ int si[4];
    if (lane == 0) { sp[wave] = bp; si[wave] = bidx; }
    __syncthreads();
    if (threadIdx.x == 0) {
        float P = sp[0]; int I = si[0];
        for (int w = 1; w < 4; ++w)
            if (sp[w] > P || (sp[w] == P && si[w] < I)) { P = sp[w]; I = si[w]; }
        best[blockIdx.x] =
            ((unsigned long long)__float_as_uint(P) << 32) |
            (unsigned long long)(0xFFFFFFFFu - (unsigned)I);
    }
}

// ---------------------------------------------------------------------------
// K3: weighted accumulation over the argmax attention row + fused finalize.
// grid = 2048 blocks (64/batch), 16 tokens/block, 4 tokens/wave.
// The last-finishing block of each batch (agent-scope counter) reduces the
// 64 partials with the same 64-lane butterfly the old k4 used -> bit-identical.
// s = cosine in [-1,1] => exp(s) safe; softmax max-shift cancels algebraically.
// ---------------------------------------------------------------------------
__global__ __launch_bounds__(256, 4) void k3_attn_row(
    const float* __restrict__ x, const float4* __restrict__ stats,
    const unsigned long long* __restrict__ best, float4* __restrict__ part,
    unsigned int* __restrict__ cnt, const float* __restrict__ fc_final_b,
    float* __restrict__ out)
{
    const int wave = threadIdx.x >> 6;
    const int lane = threadIdx.x & 63;
    const int b     = blockIdx.x >> 6;          // 64 blocks per batch
    const int tbase = (blockIdx.x & 63) * 16;

    // reduce the 32 per-block argmax candidates: u64 max butterfly (all waves
    // redundantly; lanes >=32 contribute 0 which never wins since p>0)
    unsigned long long pk = (lane < 32) ? best[b * 32 + lane] : 0ull;
    #pragma unroll
    for (int d = 32; d > 0; d >>= 1) {
        const unsigned long long o = __shfl_xor(pk, d);
        pk = o > pk ? o : pk;
    }
    const int idx = (int)(0xFFFFFFFFu - (unsigned)(pk & 0xFFFFFFFFull));

    const float* xb = x + (size_t)b * T * F;
    const int t0 = tbase + wave;                 // tokens t0, t0+4, t0+8, t0+12

    // issue ALL global loads first: 4 token rows + q row + stats
    float4 bA[3], bB[3], bC[3], bD[3], q[3];
    load_row(xb + (size_t)t0 * F,        lane, bA);
    load_row(xb + (size_t)(t0 + 4) * F,  lane, bB);
    load_row(xb + (size_t)(t0 + 8) * F,  lane, bC);
    load_row(xb + (size_t)(t0 + 12) * F, lane, bD);
    load_row(xb + (size_t)idx * F,       lane, q);
    const float4 qs  = stats[(size_t)b * T + idx];
    const float4 st0 = stats[(size_t)b * T + t0];
    const float4 st1 = stats[(size_t)b * T + t0 + 4];
    const float4 st2 = stats[(size_t)b * T + t0 + 8];
    const float4 st3 = stats[(size_t)b * T + t0 + 12];

    #pragma unroll
    for (int j = 0; j < 3; ++j) {               // q pre-scaled by 1/||q||
        q[j].x *= qs.w; q[j].y *= qs.w; q[j].z *= qs.w; q[j].w *= qs.w;
    }

    float a0 = 0.f, a1 = 0.f, a2 = 0.f, a3 = 0.f;
    #pragma unroll
    for (int j = 0; j < 3; ++j) {
        a0 += bA[j].x*q[j].x + bA[j].y*q[j].y + bA[j].z*q[j].z + bA[j].w*q[j].w;
        a1 += bB[j].x*q[j].x + bB[j].y*q[j].y + bB[j].z*q[j].z + bB[j].w*q[j].w;
        a2 += bC[j].x*q[j].x + bC[j].y*q[j].y + bC[j].z*q[j].z + bC[j].w*q[j].w;
        a3 += bD[j].x*q[j].x + bD[j].y*q[j].y + bD[j].z*q[j].z + bD[j].w*q[j].w;
    }
    // packed 4-way reduce: q0->a0, q16->a1, q32->a2, q48->a3 (same tree)
    const bool hi32 = (lane & 32) != 0;
    const bool hi16 = (lane & 16) != 0;
    float s1 = hi32 ? a0 : a2;
    float r1 = __shfl_xor(s1, 32);
    float u  = (hi32 ? a2 : a0) + r1;
    float s2 = hi32 ? a1 : a3;
    float r2 = __shfl_xor(s2, 32);
    float v2 = (hi32 ? a3 : a1) + r2;
    float s3 = hi16 ? u : v2;
    float r3 = __shfl_xor(s3, 16);
    float w  = (hi16 ? v2 : u) + r3;
    #pragma unroll
    for (int d = 8; d > 0; d >>= 1) w += __shfl_xor(w, d);
    const float c0 = __shfl(w, 0);
    const float c1 = __shfl(w, 16);
    const float c2 = __shfl(w, 32);
    const float c3 = __shfl(w, 48);

    // exp(cos)*p weights; accumulate in original sequential order
    const float w0 = expf(c0 * st0.w) * st0.x;
    const float w1 = expf(c1 * st1.w) * st1.x;
    const float w2 = expf(c2 * st2.w) * st2.x;
    const float w3 = expf(c3 * st3.w) * st3.x;
    float den = w0, n0 = w0 * st0.y, n1 = w0 * st0.z;
    den += w1; n0 += w1 * st1.y; n1 += w1 * st1.z;
    den += w2; n0 += w2 * st2.y; n1 += w2 * st2.z;
    den += w3; n0 += w3 * st3.y; n1 += w3 * st3.z;

    __shared__ float red[4][3];
    __shared__ int sIsLast;
    if (lane == 0) { red[wave][0] = den; red[wave][1] = n0; red[wave][2] = n1; }
    __syncthreads();
    if (threadIdx.x == 0) {
        float D = 0.f, N0 = 0.f, N1 = 0.f;
        for (int w_ = 0; w_ < 4; ++w_) { D += red[w_][0]; N0 += red[w_][1]; N1 += red[w_][2]; }
        part[blockIdx.x] = make_float4(D, N0, N1, 0.f);
        // release our partial, then bump the batch counter (agent scope)
        __threadfence();
        const unsigned old = __hip_atomic_fetch_add(&cnt[b], 1u,
                                __ATOMIC_ACQ_REL, __HIP_MEMORY_SCOPE_AGENT);
        sIsLast = (old == 63u);
    }
    __syncthreads();

    // last block of this batch: fused finalize (old k4, bit-identical butterfly)
    if (sIsLast && threadIdx.x < 64) {
        __builtin_amdgcn_fence(__ATOMIC_ACQUIRE, "agent");
        const float* pp = (const float*)&part[(size_t)b * 64 + threadIdx.x];
        float D  = __hip_atomic_load(pp + 0, __ATOMIC_RELAXED, __HIP_MEMORY_SCOPE_AGENT);
        float N0 = __hip_atomic_load(pp + 1, __ATOMIC_RELAXED, __HIP_MEMORY_SCOPE_AGENT);
        float N1 = __hip_atomic_load(pp + 2, __ATOMIC_RELAXED, __HIP_MEMORY_SCOPE_AGENT);
        #pragma unroll
        for (int d = 32; d > 0; d >>= 1) {
            D  += __shfl_xor(D,  d);
            N0 += __shfl_xor(N0, d);
            N1 += __shfl_xor(N1, d);
        }
        if (threadIdx.x == 0) {
            out[b * 2 + 0] = N0 / D + fc_final_b[0];
            out[b * 2 + 1] = N1 / D + fc_final_b[1];
        }
    }
}

extern "C" void kernel_launch(void* const* d_in, const int* in_sizes, int n_in,
                              void* d_out, int out_size, void* d_ws, size_t ws_size,
                              hipStream_t stream) {
    const float* x          = (const float*)d_in[0];
    const float* fc_w       = (const float*)d_in[1];
    const float* fc_b       = (const float*)d_in[2];
    const float* fc_final_w = (const float*)d_in[3];
    const float* fc_final_b = (const float*)d_in[4];
    float* out = (float*)d_out;

    char* ws = (char*)d_ws;
    unsigned long long* best = (unsigned long long*)ws;       // 8 KB
    float4* part  = (float4*)(ws + 8192);                     // 32 KB
    unsigned int* cnt = (unsigned int*)(ws + 40960);          // 128 B
    float4* stats = (float4*)(ws + 65536);                    // 512 KB

    k1_token_stats<<<dim3(BATCH * 32), 256, 0, stream>>>(
        x, fc_w, fc_b, fc_final_w, stats, best, cnt);
    k3_attn_row<<<dim3(BATCH * 64), 256, 0, stream>>>(
        x, stats, best, part, cnt, fc_final_b, out);
}

// Round 4
// 171.431 us; speedup vs baseline: 1.6550x; 1.6550x over previous
//
#include <hip/hip_runtime.h>
#include <math.h>

#define BATCH 32
#define T 1024
#define F 768

// Workspace layout (NO zero-init required anywhere):
//   [0, 8192)        : u64  best[1024]     one packed (p,idx) candidate per K1 block
//   [8192, 40960)    : f32x4 part[2048]    (den, n0, n1, 0) per token-GROUP (slot = b*64 + tbase/16)
//   [65536, 589824)  : f32x4 stats[32768]  (p, y0, y1, inv_norm) per token

__device__ __forceinline__ void load_row(const float* __restrict__ p, int lane, float4 v[3]) {
    #pragma unroll
    for (int j = 0; j < 3; ++j) v[j] = *(const float4*)(p + j * 256 + lane * 4);
}

// ---------------------------------------------------------------------------
// K1: per-token stats + per-block argmax candidate (no atomics).
// grid = 1024 blocks (32/batch), 4 waves, 32 tokens/block, 8 iters/wave.
// 2-deep token prefetch keeps ~6 KB/wave of global loads in flight.
// Packed reduce-scatter: 10 shuffles/token vs 24, identical reduction tree
// (pairing order 32,16,8,4,2,1 per value) => bit-identical results.
// ---------------------------------------------------------------------------
__global__ __launch_bounds__(256, 4) void k1_token_stats(
    const float* __restrict__ x, const float* __restrict__ fc_w,
    const float* __restrict__ fc_b, const float* __restrict__ fc_final_w,
    float4* __restrict__ stats, unsigned long long* __restrict__ best)
{
    const int wave = threadIdx.x >> 6;
    const int lane = threadIdx.x & 63;
    const int b     = blockIdx.x >> 5;          // 32 blocks per batch
    const int tbase = (blockIdx.x & 31) * 32;   // token base within batch

    // hoist weights to registers; fc_w rows collapse to their difference
    float4 wd[3], f0[3], f1[3];
    #pragma unroll
    for (int j = 0; j < 3; ++j) {
        const int off = j * 256 + lane * 4;
        float4 a = *(const float4*)(fc_w + off);
        float4 c = *(const float4*)(fc_w + F + off);
        wd[j] = make_float4(a.x - c.x, a.y - c.y, a.z - c.z, a.w - c.w);
        f0[j] = *(const float4*)(fc_final_w + off);
        f1[j] = *(const float4*)(fc_final_w + F + off);
    }
    const float bias01 = fc_b[0] - fc_b[1];

    const float* tok0 = x + ((size_t)b * T + tbase + wave) * F;

    float bp = -1.f; int bidx = 0;              // wave-local argmax (uniform)
    float4 buf[3][3];                           // 3-slot rotation, 2-deep prefetch
    load_row(tok0,           lane, buf[0]);
    load_row(tok0 + 4 * F,   lane, buf[1]);
    #pragma unroll
    for (int it = 0; it < 8; ++it) {
        const int t = tbase + it * 4 + wave;
        if (it < 6)                              // prefetch token it+2
            load_row(tok0 + (it + 2) * 4 * F, lane, buf[(it + 2) % 3]);
        const float4* v = buf[it % 3];
        float asq = 0.f, da = 0.f, a0 = 0.f, a1 = 0.f;
        #pragma unroll
        for (int j = 0; j < 3; ++j) {
            float4 w = v[j];
            asq += w.x*w.x     + w.y*w.y     + w.z*w.z     + w.w*w.w;
            da  += w.x*wd[j].x + w.y*wd[j].y + w.z*wd[j].z + w.w*wd[j].w;
            a0  += w.x*f0[j].x + w.y*f0[j].y + w.z*f0[j].z + w.w*f0[j].w;
            a1  += w.x*f1[j].x + w.y*f1[j].y + w.z*f1[j].z + w.w*f1[j].w;
        }
        // packed reduce-scatter over lane quadrants:
        //   q0 -> asq, q16 -> da, q32 -> a0, q48 -> a1
        const bool hi32 = (lane & 32) != 0;
        const bool hi16 = (lane & 16) != 0;
        float s1 = hi32 ? asq : a0;                 // give away
        float r1 = __shfl_xor(s1, 32);
        float u  = (hi32 ? a0 : asq) + r1;          // keep mine + partner's
        float s2 = hi32 ? da : a1;
        float r2 = __shfl_xor(s2, 32);
        float v2 = (hi32 ? a1 : da) + r2;
        float s3 = hi16 ? u : v2;
        float r3 = __shfl_xor(s3, 16);
        float w  = (hi16 ? v2 : u) + r3;
        #pragma unroll
        for (int d = 8; d > 0; d >>= 1) w += __shfl_xor(w, d);
        const float da_t = __shfl(w, 16);           // uniform broadcasts
        const float a0_t = __shfl(w, 32);
        const float a1_t = __shfl(w, 48);
        const float p = 1.f / (1.f + expf(da_t + bias01));  // softmax(logits)[1]
        if (lane == 0)                               // lane0's w == asq total
            stats[(size_t)b * T + t] = make_float4(p, a0_t, a1_t, 1.f / sqrtf(w));
        if (p > bp) { bp = p; bidx = t; }            // strict > keeps first max
    }

    // block candidate -> distinct slot; packed so plain u64 max == numpy argmax:
    // p > 0 => float bits order-preserving; low word 0xFFFFFFFF-idx => first-max ties
    __shared__ float sp[4]; __shared__ int si[4];
    if (lane == 0) { sp[wave] = bp; si[wave] = bidx; }
    __syncthreads();
    if (threadIdx.x == 0) {
        float P = sp[0]; int I = si[0];
        for (int w = 1; w < 4; ++w)
            if (sp[w] > P || (sp[w] == P && si[w] < I)) { P = sp[w]; I = si[w]; }
        best[blockIdx.x] =
            ((unsigned long long)__float_as_uint(P) << 32) |
            (unsigned long long)(0xFFFFFFFFu - (unsigned)I);
    }
}

// ---------------------------------------------------------------------------
// K3: weighted accumulation over the argmax attention row.
// grid = 2048 blocks (64/batch), 16 tokens/block, 4 tokens/wave.
// XCD-aligned token mapping: k1's block (b*32+i) warmed tokens [32i,32i+32)
// into XCD (i%8)'s L2 (empirical round-robin blk%8). k3 block j (XCD j&7)
// therefore handles half of a group i with i%8 == j&7:
//   i = (j&7) + 8*((j>>3)>>1), h = (j>>3)&1, tbase = 32*i + 16*h.
// part[] is indexed by TOKEN GROUP (tbase/16), not block id, so k4's
// reduction sums the same values in the same slots -> bit-identical output.
// s = cosine in [-1,1] => exp(s) safe; softmax max-shift cancels algebraically.
// ---------------------------------------------------------------------------
__global__ __launch_bounds__(256, 4) void k3_attn_row(
    const float* __restrict__ x, const float4* __restrict__ stats,
    const unsigned long long* __restrict__ best, float4* __restrict__ part)
{
    const int wave = threadIdx.x >> 6;
    const int lane = threadIdx.x & 63;
    const int b = blockIdx.x >> 6;              // 64 blocks per batch
    const int j = blockIdx.x & 63;
    const int i = (j & 7) + ((j >> 4) << 3);    // token group of 32, i%8 == XCD
    const int h = (j >> 3) & 1;                 // which 16-token half
    const int tbase = i * 32 + h * 16;

    // reduce the 32 per-block argmax candidates: u64 max butterfly (all waves
    // redundantly; lanes >=32 contribute 0 which never wins since p>0)
    unsigned long long pk = (lane < 32) ? best[b * 32 + lane] : 0ull;
    #pragma unroll
    for (int d = 32; d > 0; d >>= 1) {
        const unsigned long long o = __shfl_xor(pk, d);
        pk = o > pk ? o : pk;
    }
    const int idx = (int)(0xFFFFFFFFu - (unsigned)(pk & 0xFFFFFFFFull));

    const float* xb = x + (size_t)b * T * F;
    const int t0 = tbase + wave;                 // tokens t0, t0+4, t0+8, t0+12

    // issue ALL global loads first: 4 token rows + q row + stats
    float4 bA[3], bB[3], bC[3], bD[3], q[3];
    load_row(xb + (size_t)t0 * F,        lane, bA);
    load_row(xb + (size_t)(t0 + 4) * F,  lane, bB);
    load_row(xb + (size_t)(t0 + 8) * F,  lane, bC);
    load_row(xb + (size_t)(t0 + 12) * F, lane, bD);
    load_row(xb + (size_t)idx * F,       lane, q);
    const float4 qs  = stats[(size_t)b * T + idx];
    const float4 st0 = stats[(size_t)b * T + t0];
    const float4 st1 = stats[(size_t)b * T + t0 + 4];
    const float4 st2 = stats[(size_t)b * T + t0 + 8];
    const float4 st3 = stats[(size_t)b * T + t0 + 12];

    #pragma unroll
    for (int jj = 0; jj < 3; ++jj) {            // q pre-scaled by 1/||q||
        q[jj].x *= qs.w; q[jj].y *= qs.w; q[jj].z *= qs.w; q[jj].w *= qs.w;
    }

    float a0 = 0.f, a1 = 0.f, a2 = 0.f, a3 = 0.f;
    #pragma unroll
    for (int jj = 0; jj < 3; ++jj) {
        a0 += bA[jj].x*q[jj].x + bA[jj].y*q[jj].y + bA[jj].z*q[jj].z + bA[jj].w*q[jj].w;
        a1 += bB[jj].x*q[jj].x + bB[jj].y*q[jj].y + bB[jj].z*q[jj].z + bB[jj].w*q[jj].w;
        a2 += bC[jj].x*q[jj].x + bC[jj].y*q[jj].y + bC[jj].z*q[jj].z + bC[jj].w*q[jj].w;
        a3 += bD[jj].x*q[jj].x + bD[jj].y*q[jj].y + bD[jj].z*q[jj].z + bD[jj].w*q[jj].w;
    }
    // packed 4-way reduce: q0->a0, q16->a1, q32->a2, q48->a3 (same tree)
    const bool hi32 = (lane & 32) != 0;
    const bool hi16 = (lane & 16) != 0;
    float s1 = hi32 ? a0 : a2;
    float r1 = __shfl_xor(s1, 32);
    float u  = (hi32 ? a2 : a0) + r1;
    float s2 = hi32 ? a1 : a3;
    float r2 = __shfl_xor(s2, 32);
    float v2 = (hi32 ? a3 : a1) + r2;
    float s3 = hi16 ? u : v2;
    float r3 = __shfl_xor(s3, 16);
    float w  = (hi16 ? v2 : u) + r3;
    #pragma unroll
    for (int d = 8; d > 0; d >>= 1) w += __shfl_xor(w, d);
    const float c0 = __shfl(w, 0);
    const float c1 = __shfl(w, 16);
    const float c2 = __shfl(w, 32);
    const float c3 = __shfl(w, 48);

    // exp(cos)*p weights; accumulate in original sequential order
    const float w0 = expf(c0 * st0.w) * st0.x;
    const float w1 = expf(c1 * st1.w) * st1.x;
    const float w2 = expf(c2 * st2.w) * st2.x;
    const float w3 = expf(c3 * st3.w) * st3.x;
    float den = w0, n0 = w0 * st0.y, n1 = w0 * st0.z;
    den += w1; n0 += w1 * st1.y; n1 += w1 * st1.z;
    den += w2; n0 += w2 * st2.y; n1 += w2 * st2.z;
    den += w3; n0 += w3 * st3.y; n1 += w3 * st3.z;

    __shared__ float red[4][3];
    if (lane == 0) { red[wave][0] = den; red[wave][1] = n0; red[wave][2] = n1; }
    __syncthreads();
    if (threadIdx.x == 0) {
        float D = 0.f, N0 = 0.f, N1 = 0.f;
        for (int w_ = 0; w_ < 4; ++w_) { D += red[w_][0]; N0 += red[w_][1]; N1 += red[w_][2]; }
        part[(size_t)b * 64 + (tbase >> 4)] = make_float4(D, N0, N1, 0.f);
    }
}

// ---------------------------------------------------------------------------
// K4: one wave per batch reduces 64 partials -> out[B,2]
// ---------------------------------------------------------------------------
__global__ __launch_bounds__(64) void k4_finalize(
    const float4* __restrict__ part, const float* __restrict__ fc_final_b,
    float* __restrict__ out)
{
    const int b = blockIdx.x;
    const int lane = threadIdx.x;
    float4 v = part[(size_t)b * 64 + lane];
    float D = v.x, N0 = v.y, N1 = v.z;
    #pragma unroll
    for (int d = 32; d > 0; d >>= 1) {
        D  += __shfl_xor(D,  d);
        N0 += __shfl_xor(N0, d);
        N1 += __shfl_xor(N1, d);
    }
    if (lane == 0) {
        out[b * 2 + 0] = N0 / D + fc_final_b[0];
        out[b * 2 + 1] = N1 / D + fc_final_b[1];
    }
}

extern "C" void kernel_launch(void* const* d_in, const int* in_sizes, int n_in,
                              void* d_out, int out_size, void* d_ws, size_t ws_size,
                              hipStream_t stream) {
    const float* x          = (const float*)d_in[0];
    const float* fc_w       = (const float*)d_in[1];
    const float* fc_b       = (const float*)d_in[2];
    const float* fc_final_w = (const float*)d_in[3];
    const float* fc_final_b = (const float*)d_in[4];
    float* out = (float*)d_out;

    char* ws = (char*)d_ws;
    unsigned long long* best = (unsigned long long*)ws;       // 8 KB
    float4* part  = (float4*)(ws + 8192);                     // 32 KB
    float4* stats = (float4*)(ws + 65536);                    // 512 KB

    k1_token_stats<<<dim3(BATCH * 32), 256, 0, stream>>>(
        x, fc_w, fc_b, fc_final_w, stats, best);
    k3_attn_row<<<dim3(BATCH * 64), 256, 0, stream>>>(x, stats, best, part);
    k4_finalize<<<dim3(BATCH), 64, 0, stream>>>(part, fc_final_b, out);
}